// Round 3
// baseline (131.369 us; speedup 1.0000x reference)
//
#include <hip/hip_runtime.h>
#include <hip/hip_bf16.h>

#define NN   1024
#define FIN  128
#define FOUT 64

typedef __attribute__((ext_vector_type(8))) short short8;
typedef __attribute__((ext_vector_type(4))) float f32x4;

__device__ inline unsigned short f2bf(float x) {
    union { __hip_bfloat16 h; unsigned short u; } c;
    c.h = __float2bfloat16(x);
    return c.u;
}
__device__ inline unsigned packbf(float a, float b) {
    return (unsigned)f2bf(a) | ((unsigned)f2bf(b) << 16);
}
__device__ inline float dot4(float4 x, float4 y) {
    return x.x*y.x + x.y*y.y + x.z*y.z + x.w*y.w;
}

// ---------------- Kernel 0: wa1/wa2 = W @ a1 / W @ a2 (fp32), Wt_bf[col][k] bf16
__global__ __launch_bounds__(256) void k0_prep(
    const float* __restrict__ W, const float* __restrict__ a,
    float* __restrict__ wa1, float* __restrict__ wa2,
    unsigned short* __restrict__ wtbf)
{
    const int t = threadIdx.x;
    if (t < FIN) {
        float s1 = 0.f, s2 = 0.f;
        #pragma unroll
        for (int c = 0; c < FOUT; c += 4) {
            float4 wv  = *(const float4*)(W + t * FOUT + c);
            float4 a1v = *(const float4*)(a + c);
            float4 a2v = *(const float4*)(a + FOUT + c);
            s1 += dot4(wv, a1v);
            s2 += dot4(wv, a2v);
        }
        wa1[t] = s1; wa2[t] = s2;
    }
    const int col = t >> 2, ks = (t & 3) << 5;
    #pragma unroll
    for (int k = 0; k < 32; ++k)
        wtbf[col * FIN + ks + k] = f2bf(W[(size_t)(ks + k) * FOUT + col]);
}

// ---------------- Kernel 1: Wh via bf16 MFMA (no LDS), fp32 s1/s2 = X·wa
__global__ __launch_bounds__(256) void k1_proj(
    const float* __restrict__ X,
    const float* __restrict__ wa1, const float* __restrict__ wa2,
    const unsigned short* __restrict__ wtbf,
    unsigned short* __restrict__ whbt,   // [B][FOUT][NN] bf16
    float* __restrict__ s1g, float* __restrict__ s2g)
{
    const int t = threadIdx.x, l = t & 63, w = t >> 6;
    const int bid = blockIdx.x;            // 1024 blocks
    const int b = bid >> 4;
    const int r0 = (bid & 15) << 6;        // 64 rows/block, 16/wave
    const int r16 = l & 15;
    const int jo = (l >> 4) << 3;          // lane's k-offset within 32-k chunk
    const int row = r0 + w * 16 + r16;
    const float* xr = X + (size_t)(b * NN + row) * FIN;

    f32x4 acc[4];
    #pragma unroll
    for (int s = 0; s < 4; ++s)
        #pragma unroll
        for (int r = 0; r < 4; ++r) acc[s][r] = 0.f;
    float s1p = 0.f, s2p = 0.f;

    #pragma unroll
    for (int kc = 0; kc < 4; ++kc) {
        const int k0i = kc * 32 + jo;
        float4 xa = *(const float4*)(xr + k0i);
        float4 xb = *(const float4*)(xr + k0i + 4);
        float4 w1a = *(const float4*)(wa1 + k0i);
        float4 w1b = *(const float4*)(wa1 + k0i + 4);
        float4 w2a = *(const float4*)(wa2 + k0i);
        float4 w2b = *(const float4*)(wa2 + k0i + 4);
        s1p += dot4(xa, w1a) + dot4(xb, w1b);
        s2p += dot4(xa, w2a) + dot4(xb, w2b);

        union { unsigned u[4]; short8 s8; } A;
        A.u[0] = packbf(xa.x, xa.y); A.u[1] = packbf(xa.z, xa.w);
        A.u[2] = packbf(xb.x, xb.y); A.u[3] = packbf(xb.z, xb.w);
        #pragma unroll
        for (int s = 0; s < 4; ++s) {
            short8 bfv = *(const short8*)(wtbf + (s * 16 + r16) * FIN + k0i);
            acc[s] = __builtin_amdgcn_mfma_f32_16x16x32_bf16(A.s8, bfv, acc[s], 0, 0, 0);
        }
    }

    // fp32 row scores (lanes l, l^16, l^32, l^48 share row r16)
    s1p += __shfl_xor(s1p, 16, 64); s1p += __shfl_xor(s1p, 32, 64);
    s2p += __shfl_xor(s2p, 16, 64); s2p += __shfl_xor(s2p, 32, 64);
    if (jo == 0) {
        s1g[b * NN + row] = s1p;
        s2g[b * NN + row] = s2p;
    }

    // D layout: row_in_tile = (l>>4)*4 + rr, col = s*16 + r16 -> transposed whbt write
    const int rb = (l >> 4) << 2;
    #pragma unroll
    for (int s = 0; s < 4; ++s) {
        unsigned d0 = packbf(acc[s][0], acc[s][1]);
        unsigned d1 = packbf(acc[s][2], acc[s][3]);
        *(uint2*)(whbt + (size_t)(b * FOUT + s * 16 + r16) * NN + r0 + w * 16 + rb)
            = make_uint2(d0, d1);
    }
}

// ---------------- Kernel 1b: s2max per batch
__global__ __launch_bounds__(256) void k1b_max(
    const float* __restrict__ s2g, float* __restrict__ s2max)
{
    int b = blockIdx.x, t = threadIdx.x;
    float m = -3.4e38f;
    #pragma unroll
    for (int i = 0; i < 4; ++i) m = fmaxf(m, s2g[b * NN + t + i * 256]);
    #pragma unroll
    for (int d = 1; d <= 32; d <<= 1) m = fmaxf(m, __shfl_xor(m, d, 64));
    __shared__ float red[4];
    if ((t & 63) == 0) red[t >> 6] = m;
    __syncthreads();
    if (t == 0) s2max[b] = fmaxf(fmaxf(red[0], red[1]), fmaxf(red[2], red[3]));
}

// ---------------- Kernel 2: barrier-free fused softmax + P@Wh,
// 8-deep adjacency prefetch per 128-j tile, P built in A-fragment layout.
__global__ __launch_bounds__(256) void k2_attn(
    const int* __restrict__ adj,
    const unsigned short* __restrict__ whbt,
    const float* __restrict__ s1g, const float* __restrict__ s2g,
    const float* __restrict__ s2maxg,
    float* __restrict__ outg)
{
    const int t = threadIdx.x, l = t & 63, w = t >> 6;
    const int bid = blockIdx.x;            // 1024 blocks
    const int b = bid >> 4;
    const int i0 = (bid & 15) << 6;
    const int r16 = l & 15;
    const int jo = (l >> 4) << 3;
    const int row = i0 + w * 16 + r16;

    const float s2m = s2maxg[b];
    const float s1v = s1g[b * NN + row];
    const float tt = s1v + s2m;
    const float Mr = fmaxf(tt, 0.1f * tt); // exact upper bound on row max (leaky monotone)

    const int* adjr = adj + (size_t)b * NN * NN + (size_t)row * NN;
    const float* s2r = s2g + b * NN;
    const unsigned short* wb = whbt + (size_t)b * FOUT * NN + (size_t)r16 * NN;

    f32x4 acc[4];
    #pragma unroll
    for (int s = 0; s < 4; ++s)
        #pragma unroll
        for (int r = 0; r < 4; ++r) acc[s][r] = 0.f;
    float den = 0.f;

    for (int jt = 0; jt < NN; jt += 128) {
        // hoisted: 8 int4 adjacency loads in flight (128 B/lane)
        int4 A0[4], A1[4];
        #pragma unroll
        for (int c = 0; c < 4; ++c) {
            A0[c] = *(const int4*)(adjr + jt + c * 32 + jo);
            A1[c] = *(const int4*)(adjr + jt + c * 32 + jo + 4);
        }
        #pragma unroll
        for (int c = 0; c < 4; ++c) {
            const int j0 = jt + c * 32 + jo;
            float4 sa = *(const float4*)(s2r + j0);
            float4 sb = *(const float4*)(s2r + j0 + 4);
            short8 bfv[4];
            #pragma unroll
            for (int s = 0; s < 4; ++s)
                bfv[s] = *(const short8*)(wb + (size_t)s * (16 * NN) + j0);

            const float sv[8] = {sa.x, sa.y, sa.z, sa.w, sb.x, sb.y, sb.z, sb.w};
            const int   am[8] = {A0[c].x, A0[c].y, A0[c].z, A0[c].w,
                                 A1[c].x, A1[c].y, A1[c].z, A1[c].w};
            unsigned pk[4];
            #pragma unroll
            for (int e = 0; e < 4; ++e) {
                float xa = s1v + sv[2*e];
                float xb = s1v + sv[2*e+1];
                float ea = fmaxf(xa, 0.1f * xa) - Mr;
                float eb = fmaxf(xb, 0.1f * xb) - Mr;
                float pa = am[2*e]   > 0 ? __expf(ea) : 0.f;
                float pb = am[2*e+1] > 0 ? __expf(eb) : 0.f;
                den += pa + pb;
                pk[e] = packbf(pa, pb);
            }
            union { unsigned u[4]; short8 s8; } A;
            A.u[0] = pk[0]; A.u[1] = pk[1]; A.u[2] = pk[2]; A.u[3] = pk[3];
            #pragma unroll
            for (int s = 0; s < 4; ++s)
                acc[s] = __builtin_amdgcn_mfma_f32_16x16x32_bf16(A.s8, bfv[s], acc[s], 0, 0, 0);
        }
    }

    den += __shfl_xor(den, 16, 64);
    den += __shfl_xor(den, 32, 64);

    const int rb = (l >> 4) << 2;
    float inv[4];
    #pragma unroll
    for (int rr = 0; rr < 4; ++rr) {
        float dd = __shfl(den, rb + rr, 64);
        inv[rr] = dd > 0.f ? 1.f / dd : 0.f;
    }
    float* orow = outg + ((size_t)(b * NN + i0 + w * 16 + rb)) * FOUT;
    #pragma unroll
    for (int s = 0; s < 4; ++s)
        #pragma unroll
        for (int rr = 0; rr < 4; ++rr) {
            float v = acc[s][rr] * inv[rr];
            float res = v > 0.f ? v : (__expf(v) - 1.f);
            orow[(size_t)rr * FOUT + s * 16 + r16] = res;
        }
}

extern "C" void kernel_launch(void* const* d_in, const int* in_sizes, int n_in,
                              void* d_out, int out_size, void* d_ws, size_t ws_size,
                              hipStream_t stream) {
    const float* atoms = (const float*)d_in[0];
    const int*   adj   = (const int*)d_in[1];
    const float* W     = (const float*)d_in[2];
    const float* a     = (const float*)d_in[3];
    float* out = (float*)d_out;

    char* ws = (char*)d_ws;
    unsigned short* whbt   = (unsigned short*)ws;                    // 8 MB bf16
    float* s1g    = (float*)(ws + (8u << 20));                       // 256 KB
    float* s2g    = (float*)(ws + (8u << 20) + (256u << 10));        // 256 KB
    float* s2maxg = (float*)(ws + (8u << 20) + (512u << 10));        // 256 B
    float* wa1    = (float*)(ws + (8u << 20) + (513u << 10));        // 512 B
    float* wa2    = (float*)(ws + (8u << 20) + (514u << 10));        // 512 B
    unsigned short* wtbf = (unsigned short*)(ws + (8u << 20) + (515u << 10)); // 16 KB

    k0_prep<<<1, 256, 0, stream>>>(W, a, wa1, wa2, wtbf);
    k1_proj<<<1024, 256, 0, stream>>>(atoms, wa1, wa2, wtbf, whbt, s1g, s2g);
    k1b_max<<<64, 256, 0, stream>>>(s2g, s2maxg);
    k2_attn<<<1024, 256, 0, stream>>>(adj, whbt, s1g, s2g, s2maxg, out);
}